// Round 12
// baseline (206.598 us; speedup 1.0000x reference)
//
#include <hip/hip_runtime.h>
#include <stdint.h>

typedef uint16_t u16;
typedef __attribute__((ext_vector_type(8))) short bf16x8;    // 8 bf16 (4 VGPRs)
typedef __attribute__((ext_vector_type(4))) float f32x4;     // MFMA C/D 16x16
typedef __attribute__((ext_vector_type(16))) float f32x16;   // MFMA C/D 32x32

#define EMB 768
#define NH 12
#define DK 64
#define BB 2
#define SS 2048
#define SCL 0.1803368801111244f   // 0.125 * log2(e)  (folded into Wq at pack time)
#define M0  24.0f                 // fixed softmax offset (log2 domain)

// gfx950 HW packed cvt: lo16 = bf16(a), hi16 = bf16(b), RNE
__device__ __forceinline__ uint32_t pk2(float a, float b) {
  uint32_t d;
  asm("v_cvt_pk_bf16_f32 %0, %1, %2" : "=v"(d) : "v"(a), "v"(b));
  return d;
}

__device__ __forceinline__ void gld16(const u16* g, u16* l) {
  __builtin_amdgcn_global_load_lds((const __attribute__((address_space(1))) void*)g,
                                   (__attribute__((address_space(3))) void*)l, 16, 0, 0);
}

// ---------------- pack_w: tiled-transpose weights only (576 blocks) ----------------
// 64x64 tile transpose through LDS (pad 65 -> <=2-way banks).
//   blocks 0..431: Wq/Wk/Wv  [h][e][d] -> wqkvT[z][n=h*64+d][e]   (z==0 scaled by SCL)
//   blocks 432..575: W       [e][n]    -> wT[n][e]
__global__ void pack_w(const float* __restrict__ wq, const float* __restrict__ wk,
                       const float* __restrict__ wv, const float* __restrict__ w,
                       u16* __restrict__ wqkvT, u16* __restrict__ wT) {
  __shared__ float L[65 * 64];              // 16.6 KB transpose tile
  const int bid = blockIdx.x, tid = threadIdx.x;
  const float* srcBase;
  int srcRowStride;
  u16* outBase;
  float scale = 1.0f;
  if (bid < 432) {
    int z = bid / 144, rest = bid - z * 144;
    int h = rest / 12, et = rest - h * 12;
    const float* src = z == 0 ? wq : (z == 1 ? wk : wv);
    srcBase = src + (size_t)h * (EMB * DK) + (size_t)(et * 64) * DK;   // + e*64 + d
    srcRowStride = DK;
    outBase = wqkvT + (size_t)z * (EMB * EMB) + (size_t)(h * 64) * EMB + et * 64; // + d*768 + e
    if (z == 0) scale = SCL;
  } else {
    int idx = bid - 432;
    int nt = idx / 12, et = idx - nt * 12;
    srcBase = w + (size_t)(et * 64) * EMB + nt * 64;                   // + e*768 + n'
    srcRowStride = EMB;
    outBase = wT + (size_t)(nt * 64) * EMB + et * 64;                  // + n'*768 + e
  }
  {   // coalesced read: thread = (row e = tid>>2, 16 cols at d0=(tid&3)*16); store L[e + 65*d]
    int e = tid >> 2, d0 = (tid & 3) * 16;
    const float* s_ = srcBase + (size_t)e * srcRowStride + d0;
    float4 v0 = *(const float4*)s_,       v1 = *(const float4*)(s_ + 4);
    float4 v2 = *(const float4*)(s_ + 8), v3 = *(const float4*)(s_ + 12);
    float tv[16] = { v0.x, v0.y, v0.z, v0.w, v1.x, v1.y, v1.z, v1.w,
                     v2.x, v2.y, v2.z, v2.w, v3.x, v3.y, v3.z, v3.w };
#pragma unroll
    for (int j = 0; j < 16; ++j) L[e + 65 * (d0 + j)] = tv[j];
  }
  __syncthreads();
  {   // coalesced write: thread = (out-row d = tid>>2, 16 cols at e0=(tid&3)*16)
    int d = tid >> 2, e0 = (tid & 3) * 16;
    uint32_t pk[8];
#pragma unroll
    for (int j = 0; j < 8; ++j)
      pk[j] = pk2(L[e0 + 2 * j + 65 * d] * scale, L[e0 + 2 * j + 1 + 65 * d] * scale);
    u16* o = outBase + (size_t)d * EMB + e0;
    *(uint4*)o = *(uint4*)pk;
    *(uint4*)(o + 8) = *(uint4*)(pk + 4);
  }
}

// ---------------- pipelined GEMM cores (C = A * Bt^T), BK=64, 8-slot XOR swizzle ----------------
// R9's proven discipline: __syncthreads, LDS dest LINEAR for gld16, pre-swizzled global
// source. 12 K-steps, 16 MFMA/step. slot ^= (row&7); read key qx8 = (ks*4+quad)^(c&7).
// Measured 0 bank conflicts.

// gemm_qkv core: A f32 global->regs (pk2-cvt, swizzled ds_write); Bt bf16 via gld16. 64x128 tile.
__device__ __forceinline__ void gemm_f32A_pipe(const float* __restrict__ A,
                                               const u16* __restrict__ Bt,
                                               int m0, int n0, u16* As, u16* Bs,
                                               f32x4 (&acc)[2][4]) {
  const int tid = threadIdx.x;
  const int lane = tid & 63, quad = lane >> 4, c = lane & 15;
  const int wr = (tid >> 6) >> 1, wc = (tid >> 6) & 1;
  const int arow = tid >> 2, a4 = tid & 3;          // A: 64 rows x 64 f32, 16 f32/thread
  const int s0 = (2 * a4) ^ (arow & 7);             // swizzled 16B-slot for lo 8 cols
  const int s1 = (2 * a4 + 1) ^ (arow & 7);         // swizzled 16B-slot for hi 8 cols
  float4 a0, a1, a2, a3;
#define LOAD_A(kk)                                                     \
  {                                                                    \
    const float* src = A + (size_t)(m0 + arow) * EMB + (kk) + a4 * 16; \
    a0 = *(const float4*)src;       a1 = *(const float4*)(src + 4);    \
    a2 = *(const float4*)(src + 8); a3 = *(const float4*)(src + 12);   \
  }
#define ISSUE_B(kk, buf)                                               \
  _Pragma("unroll")                                                    \
  for (int r = 0; r < 4; ++r) {                                        \
    int bo = r * 4096 + tid * 16;   /* byte off in 128x64u16 (128B/row) */ \
    int brow = bo >> 7, bslot = (bo >> 4) & 7;                         \
    gld16(Bt + (size_t)(n0 + brow) * EMB + (kk) + (bslot ^ (brow & 7)) * 8, \
          Bs + (buf) * 8192 + (bo >> 1));        /* LDS dest linear */ \
  }
  LOAD_A(0); ISSUE_B(0, 0);
  for (int kk = 0; kk < EMB; kk += 64) {
    const int buf = (kk >> 6) & 1;
    {                                             // write A(kk) regs -> As[buf] (swizzled slots)
      uint4 p0 = { pk2(a0.x, a0.y), pk2(a0.z, a0.w), pk2(a1.x, a1.y), pk2(a1.z, a1.w) };
      uint4 p1 = { pk2(a2.x, a2.y), pk2(a2.z, a2.w), pk2(a3.x, a3.y), pk2(a3.z, a3.w) };
      *(uint4*)(As + buf * 4096 + arow * 64 + s0 * 8) = p0;
      *(uint4*)(As + buf * 4096 + arow * 64 + s1 * 8) = p1;
    }
    __syncthreads();                              // drains B(kk) DMA + A writes
    if (kk + 64 < EMB) { LOAD_A(kk + 64); ISSUE_B(kk + 64, buf ^ 1); }
    const u16* Ab = As + buf * 4096;
    const u16* Bb = Bs + buf * 8192;
#pragma unroll
    for (int ks = 0; ks < 2; ++ks) {
      const int qx8 = (ks * 4 + quad) ^ (c & 7);
      bf16x8 af[2], bfr[4];
#pragma unroll
      for (int i = 0; i < 2; ++i)
        af[i] = *(const bf16x8*)(Ab + (wr * 32 + i * 16 + c) * 64 + qx8 * 8);
#pragma unroll
      for (int j = 0; j < 4; ++j)
        bfr[j] = *(const bf16x8*)(Bb + (wc * 64 + j * 16 + c) * 64 + qx8 * 8);
#pragma unroll
      for (int i = 0; i < 2; ++i)
#pragma unroll
        for (int j = 0; j < 4; ++j)
          acc[i][j] = __builtin_amdgcn_mfma_f32_16x16x32_bf16(af[i], bfr[j], acc[i][j], 0, 0, 0);
    }
  }
#undef LOAD_A
#undef ISSUE_B
}

// gemm_out core: both operands bf16 via gld16, pre-swizzled sources. 64x64 tile, acc[2][2].
__device__ __forceinline__ void gemm_bf16A_pipe(const u16* __restrict__ A,
                                                const u16* __restrict__ Bt,
                                                int m0, int n0, u16* As, u16* Bs,
                                                f32x4 (&acc)[2][2]) {
  const int tid = threadIdx.x;
  const int lane = tid & 63, quad = lane >> 4, c = lane & 15;
  const int wr = (tid >> 6) >> 1, wc = (tid >> 6) & 1;
#define ISSUE_AB(kk, buf)                                              \
  {                                                                    \
    _Pragma("unroll")                                                  \
    for (int r = 0; r < 2; ++r) {   /* A: 64x64u16 = 8KB/buf */        \
      int ao = r * 4096 + tid * 16;                                    \
      int arw = ao >> 7, asl = (ao >> 4) & 7;                          \
      gld16(A + (size_t)(m0 + arw) * EMB + (kk) + (asl ^ (arw & 7)) * 8, \
            As + (buf) * 4096 + (ao >> 1));                            \
    }                                                                  \
    _Pragma("unroll")                                                  \
    for (int r = 0; r < 2; ++r) {   /* B: 64x64u16 = 8KB/buf */        \
      int bo = r * 4096 + tid * 16;                                    \
      int brw = bo >> 7, bsl = (bo >> 4) & 7;                          \
      gld16(Bt + (size_t)(n0 + brw) * EMB + (kk) + (bsl ^ (brw & 7)) * 8, \
            Bs + (buf) * 4096 + (bo >> 1));                            \
    }                                                                  \
  }
  ISSUE_AB(0, 0);
  for (int kk = 0; kk < EMB; kk += 64) {
    const int buf = (kk >> 6) & 1;
    __syncthreads();                              // drains DMA(kk)
    if (kk + 64 < EMB) { ISSUE_AB(kk + 64, buf ^ 1); }
    const u16* Ab = As + buf * 4096;
    const u16* Bb = Bs + buf * 4096;
#pragma unroll
    for (int ks = 0; ks < 2; ++ks) {
      const int qx8 = (ks * 4 + quad) ^ (c & 7);
      bf16x8 af[2], bfr[2];
#pragma unroll
      for (int i = 0; i < 2; ++i)
        af[i] = *(const bf16x8*)(Ab + (wr * 32 + i * 16 + c) * 64 + qx8 * 8);
#pragma unroll
      for (int j = 0; j < 2; ++j)
        bfr[j] = *(const bf16x8*)(Bb + (wc * 32 + j * 16 + c) * 64 + qx8 * 8);
#pragma unroll
      for (int i = 0; i < 2; ++i)
#pragma unroll
        for (int j = 0; j < 2; ++j)
          acc[i][j] = __builtin_amdgcn_mfma_f32_16x16x32_bf16(af[i], bfr[j], acc[i][j], 0, 0, 0);
    }
  }
#undef ISSUE_AB
}

// blocks [0,1152): z=0: Q -> Qp; z=1: K -> Kp; z=2: V -> Vt[bh][d][t].
// blocks [1152,3200): mask repack rider (consumed only by the LATER attn kernel).
__launch_bounds__(256, 3)
__global__ void gemm_qkv(const float* __restrict__ q, const float* __restrict__ k,
                         const float* __restrict__ v, const u16* __restrict__ wt3,
                         const int* __restrict__ mask,
                         u16* __restrict__ Qp, u16* __restrict__ Kp, u16* __restrict__ Vt,
                         uint64_t* __restrict__ bits) {
  __shared__ __align__(16) u16 As[2 * 64 * 64];    // 16 KB dbuf
  __shared__ __align__(16) u16 Bs[2 * 128 * 64];   // 32 KB dbuf
  const int id = blockIdx.x;
  if (id >= 1152) {                          // ---- mask repack rider ----
    uint32_t widx = (uint32_t)(id - 1152) * 256 + threadIdx.x;  // [0, 524288)
    uint32_t wv64 = widx >> 6;
    uint32_t lane = widx & 63;
    uint32_t b  = wv64 >> 12;
    uint32_t qg = (wv64 >> 6) & 63;
    uint32_t tg = wv64 & 63;
    uint32_t c = lane & 31, hi = lane >> 5;
    const int* mp = mask + (((size_t)b * 2048 + qg * 32 + c) * 2048 + tg * 32 + hi * 4);
    int4 q0 = *(const int4*)mp;
    int4 q1 = *(const int4*)(mp + 8);
    int4 q2 = *(const int4*)(mp + 16);
    int4 q3 = *(const int4*)(mp + 24);
    uint64_t* wout = bits + (size_t)wv64 * 16;
    unsigned long long ball;
#define BAL(u, arr)                                                   \
    ball = __ballot(arr.x != 0); if (lane == 0) wout[u * 4 + 0] = ball; \
    ball = __ballot(arr.y != 0); if (lane == 0) wout[u * 4 + 1] = ball; \
    ball = __ballot(arr.z != 0); if (lane == 0) wout[u * 4 + 2] = ball; \
    ball = __ballot(arr.w != 0); if (lane == 0) wout[u * 4 + 3] = ball;
    BAL(0, q0) BAL(1, q1) BAL(2, q2) BAL(3, q3)
#undef BAL
    return;
  }
  const int xcd = id & 7, s = id >> 3;       // s: 0..143
  const int panel = xcd * 24 + s / 6;        // 0..191 (z*64 + mtile)
  const int ntile = s - (s / 6) * 6;
  const int z = panel >> 6, mt = panel & 63;
  const int m0 = mt * 64, n0 = ntile * 128;
  const float* A = z == 0 ? q : (z == 1 ? k : v);
  const u16* Bt = wt3 + (size_t)z * EMB * EMB;
  f32x4 acc[2][4];
  const f32x4 fz = {0.f, 0.f, 0.f, 0.f};
#pragma unroll
  for (int i = 0; i < 2; ++i)
#pragma unroll
    for (int j = 0; j < 4; ++j) acc[i][j] = fz;
  gemm_f32A_pipe(A, Bt, m0, n0, As, Bs, acc);
  const int tid = threadIdx.x, lane = tid & 63, quad = lane >> 4, c = lane & 15;
  const int wr = (tid >> 6) >> 1, wc = (tid >> 6) & 1;
  if (z < 2) {
    u16* C = z == 0 ? Qp : Kp;
#pragma unroll
    for (int i = 0; i < 2; ++i)
#pragma unroll
      for (int j = 0; j < 4; ++j) {
        int row = m0 + wr * 32 + i * 16 + quad * 4;
        int col = n0 + wc * 64 + j * 16 + c;
#pragma unroll
        for (int r = 0; r < 4; r += 2) {
          uint32_t d = pk2(acc[i][j][r], acc[i][j][r + 1]);
          C[(size_t)(row + r) * EMB + col] = (u16)d;
          C[(size_t)(row + r + 1) * EMB + col] = (u16)(d >> 16);
        }
      }
  } else {
#pragma unroll
    for (int i = 0; i < 2; ++i)
#pragma unroll
      for (int j = 0; j < 4; ++j) {
        int row = m0 + wr * 32 + i * 16 + quad * 4;   // + r -> consecutive s
        int col = n0 + wc * 64 + j * 16 + c;          // n = h*64+d
        int b = row >> 11, ss = row & 2047;
        int h = col >> 6, d = col & 63;
        uint2 pk = { pk2(acc[i][j][0], acc[i][j][1]), pk2(acc[i][j][2], acc[i][j][3]) };
        *(uint2*)(Vt + ((size_t)(b * NH + h) * DK + d) * SS + ss) = pk;
      }
  }
}

// 1-D grid 768 (64x64 tiles -> 3 blocks/CU exact), XCD-panel swizzle: 8 panels x 12 n-tiles/XCD.
__launch_bounds__(256, 4)
__global__ void gemm_out(const u16* __restrict__ A, const u16* __restrict__ Bt,
                         float* __restrict__ C) {
  __shared__ __align__(16) u16 As[2 * 64 * 64];    // 16 KB dbuf
  __shared__ __align__(16) u16 Bs[2 * 64 * 64];    // 16 KB dbuf
  const int id = blockIdx.x;                 // 0..767
  const int xcd = id & 7, s = id >> 3;       // s: 0..95
  const int panel = xcd * 8 + s / 12;        // 0..63
  const int ntile = s - (s / 12) * 12;       // 0..11
  const int m0 = panel * 64, n0 = ntile * 64;
  f32x4 acc[2][2];
  const f32x4 fz = {0.f, 0.f, 0.f, 0.f};
#pragma unroll
  for (int i = 0; i < 2; ++i)
#pragma unroll
    for (int j = 0; j < 2; ++j) acc[i][j] = fz;
  gemm_bf16A_pipe(A, Bt, m0, n0, As, Bs, acc);
  const int tid = threadIdx.x, lane = tid & 63, quad = lane >> 4, c = lane & 15;
  const int wr = (tid >> 6) >> 1, wc = (tid >> 6) & 1;
#pragma unroll
  for (int i = 0; i < 2; ++i)
#pragma unroll
    for (int j = 0; j < 2; ++j)
#pragma unroll
      for (int r = 0; r < 4; ++r) {
        int row = m0 + wr * 32 + i * 16 + quad * 4 + r;
        int col = n0 + wc * 32 + j * 16 + c;
        C[(size_t)row * EMB + col] = acc[i][j][r];   // raw fp32
      }
}

// ---------------- flash attention v7: v6 + conflict-free XOR-swizzled K/V tiles ----------------
// Grid 768 (1D, XCD-swizzled): block = (bh, 64-q tile). 8 waves = (wq2: q 32-group) x (th: t slice).
// K tile [2][128][64] (stride 64 u16 = 8x16B slots, slot ^= row&7);
// V tile [2][64][128] (stride 128 u16 = 16x16B slots, slot ^= row&15).
// Bank enumeration: all four access patterns (K/V write, K/V fragment read) land at the
// wave64 minimum 8 dwords/bank -> 0 conflicts (was 4-way on the padded 72/136 layouts).
__launch_bounds__(512, 4)
__global__ void attn(const u16* __restrict__ Qp, const u16* __restrict__ Kp,
                     const u16* __restrict__ Vt, const uint64_t* __restrict__ MW,
                     u16* __restrict__ AO) {
  // tiles: K 16384 u16 + V 16384 u16 = 65536 B; reduction overlay needs 67584 B
  __shared__ __align__(16) u16 sm[33792];
  u16* Ks0 = sm;                    // [2][128][64]
  u16* Vs0 = sm + 2 * 128 * 64;     // [2][64][128]

  const int tid = threadIdx.x, lane = tid & 63;
  const int c = lane & 31, hi = lane >> 5;
  const int w = tid >> 6;
  const int wq2 = w >> 2, th = w & 3;

  // XCD swizzle: blockIdx.x % 8 = XCD -> all 32 q-tiles of a head stay on one XCD (K/V L2-resident)
  const int wid = blockIdx.x;
  const int xcd = wid & 7, slot = wid >> 3;        // slot 0..95
  const int bh = xcd + 8 * (slot >> 5);            // 0..23
  const int mtile = slot & 31;
  const int b = bh / NH, h = bh - b * NH;
  const int m0 = mtile * 64;

  const size_t qkbase = (size_t)b * SS * EMB + (size_t)h * DK;
  const size_t vtbase = (size_t)bh * DK * SS;

  // Q fragments (B-operand): lane holds Q[q = m0+wq2*32+c][k = ks*16 + hi*8 + e]
  bf16x8 aq[4];
  {
    const u16* qr = Qp + qkbase + (size_t)(m0 + wq2 * 32 + c) * EMB + hi * 8;
    aq[0] = *(const bf16x8*)(qr);
    aq[1] = *(const bf16x8*)(qr + 16);
    aq[2] = *(const bf16x8*)(qr + 32);
    aq[3] = *(const bf16x8*)(qr + 48);
  }

  // staging: K tile 128x64, V^T tile 64x128 -> 32B per thread each array
  const int srK = tid >> 2, scA = tid & 3;         // K row, 2-slot group
  const int srV = tid >> 3, scB = tid & 7;         // V row, 2-slot group
  const u16* gK = Kp + qkbase + (size_t)srK * EMB + scA * 16;
  const u16* gV = Vt + vtbase + (size_t)srV * SS + scB * 16;
  bf16x8 kr0, kr1, vr0, vr1;
#define LOADKV(t0) {                                             \
    const u16* gk_ = gK + (size_t)(t0) * EMB;                    \
    kr0 = *(const bf16x8*)gk_; kr1 = *(const bf16x8*)(gk_ + 8);  \
    const u16* gv_ = gV + (t0);                                  \
    vr0 = *(const bf16x8*)gv_; vr1 = *(const bf16x8*)(gv_ + 8); }
#define STOREKV(buf) {                                           \
    u16* kwp = Ks0 + (buf) * 8192 + srK * 64;                    \
    *(bf16x8*)(kwp + ((2 * scA)     ^ (srK & 7)) * 8) = kr0;     \
    *(bf16x8*)(kwp + ((2 * scA + 1) ^ (srK & 7)) * 8) = kr1;     \
    u16* vwp = Vs0 + (buf) * 8192 + srV * 128;                   \
    *(bf16x8*)(vwp + ((2 * scB)     ^ (srV & 15)) * 8) = vr0;    \
    *(bf16x8*)(vwp + ((2 * scB + 1) ^ (srV & 15)) * 8) = vr1; }

  // wave-uniform mask word base (scalar loads)
  const int thu = __builtin_amdgcn_readfirstlane(th);
  const int qgu = __builtin_amdgcn_readfirstlane(mtile * 2 + wq2);
  const uint64_t* mwb = MW + (((size_t)b * 64 + qgu) * 64) * 16 + thu * 16;
#define LOADMSK(m, it) {                                         \
    const uint64_t* mp_ = mwb + (size_t)(it) * 64;               \
    _Pragma("unroll")                                            \
    for (int r_ = 0; r_ < 16; ++r_) m[r_] = mp_[r_]; }

  float fNEG = -1e9f, fM0 = -M0;
  float lr = 0.f;
  f32x16 o0, o1;
#pragma unroll
  for (int r_ = 0; r_ < 16; ++r_) { o0[r_] = 0.f; o1[r_] = 0.f; }

  uint64_t mA[16], mB[16];
  LOADKV(0); LOADMSK(mA, 0);

#define BODY(it, buf, mc, mn) {                                                   \
    STOREKV(buf);                                                                 \
    __syncthreads();                                                              \
    if ((it) < 15) { LOADKV(((it) + 1) * 128); LOADMSK(mn, (it) + 1); }           \
    /* C-init: s[r] = maskbit ? -M0 : -1e9  (one cndmask/elem, SGPR-pair mask) */ \
    f32x16 s;                                                                     \
    _Pragma("unroll")                                                             \
    for (int r_ = 0; r_ < 16; ++r_) {                                             \
      float t_;                                                                   \
      asm("v_cndmask_b32 %0, %1, %2, %3"                                          \
          : "=v"(t_) : "v"(fNEG), "v"(fM0), "s"(mc[r_]));                         \
      s[r_] = t_;                                                                 \
    }                                                                             \
    /* S^T = K * Q^T over k=64 (4 chunks); swizzled K slots */                    \
    const u16* kb_ = Ks0 + (buf) * 8192 + (th * 32 + c) * 64;                     \
    _Pragma("unroll")                                                             \
    for (int ks_ = 0; ks_ < 4; ++ks_) {                                           \
      bf16x8 kf_ = *(const bf16x8*)(kb_ + ((2 * ks_ + hi) ^ (c & 7)) * 8);        \
      s = __builtin_amdgcn_mfma_f32_32x32x16_bf16(kf_, aq[ks_], s, 0, 0, 0);      \
    }                                                                             \
    /* p = exp2(s); masked entries -> exp2(-1e9) = 0 */                           \
    _Pragma("unroll")                                                             \
    for (int r_ = 0; r_ < 16; ++r_) s[r_] = __builtin_amdgcn_exp2f(s[r_]);        \
    lr += ((s[0] + s[1]) + (s[2] + s[3])) + ((s[4] + s[5]) + (s[6] + s[7]))       \
        + ((s[8] + s[9]) + (s[10] + s[11])) + ((s[12] + s[13]) + (s[14] + s[15]));\
    /* in-register P -> PV B-frags: 8 pk2 + 4 permlane32_swap */                  \
    uint32_t x0 = pk2(s[0], s[1]),  x1 = pk2(s[2], s[3]);                         \
    uint32_t y0 = pk2(s[4], s[5]),  y1 = pk2(s[6], s[7]);                         \
    uint32_t z0 = pk2(s[8], s[9]),  z1 = pk2(s[10], s[11]);                       \
    uint32_t w0 = pk2(s[12], s[13]), w1 = pk2(s[14], s[15]);                      \
    asm("v_permlane32_swap_b32 %0, %1" : "+v"(x0), "+v"(y0));                     \
    asm("v_permlane32_swap_b32 %0, %1" : "+v"(x1), "+v"(y1));                     \
    asm("v_permlane32_swap_b32 %0, %1" : "+v"(z0), "+v"(w0));                     \
    asm("v_permlane32_swap_b32 %0, %1" : "+v"(z1), "+v"(w1));                     \
    bf16x8 pa0, pa1;                                                              \
    { union { uint32_t u[4]; bf16x8 v; } cv;                                      \
      cv.u[0] = x0; cv.u[1] = x1; cv.u[2] = y0; cv.u[3] = y1; pa0 = cv.v;         \
      cv.u[0] = z0; cv.u[1] = z1; cv.u[2] = w0; cv.u[3] = w1; pa1 = cv.v; }       \
    /* O^T += V^T * P^T : 2 d-groups x 2 t-chunks; swizzled V slots */            \
    const u16* vb_ = Vs0 + (buf) * 8192;                                          \
    const int vky = c & 15, vsl = 4 * th + hi;                                    \
    {                                                                             \
      bf16x8 vf_;                                                                 \
      vf_ = *(const bf16x8*)(vb_ + c * 128 + (vsl ^ vky) * 8);                    \
      o0 = __builtin_amdgcn_mfma_f32_32x32x16_bf16(vf_, pa0, o0, 0, 0, 0);        \
      vf_ = *(const bf16x8*)(vb_ + c * 128 + ((vsl + 2) ^ vky) * 8);              \
      o0 = __builtin_amdgcn_mfma_f32_32x32x16_bf16(vf_, pa1, o0, 0, 0, 0);        \
      vf_ = *(const bf16x8*)(vb_ + (c + 32) * 128 + (vsl ^ vky) * 8);             \
      o1 = __builtin_amdgcn_mfma_f32_32x32x16_bf16(vf_, pa0, o1, 0, 0, 0);        \
      vf_ = *(const bf16x8*)(vb_ + (c + 32) * 128 + ((vsl + 2) ^ vky) * 8);       \
      o1 = __builtin_amdgcn_mfma_f32_32x32x16_bf16(vf_, pa1, o1, 0, 0, 0);        \
    } }

  for (int i2 = 0; i2 < 8; ++i2) {
    BODY(i2 * 2,     0, mA, mB)
    BODY(i2 * 2 + 1, 1, mB, mA)
  }
#undef BODY
#undef LOADKV
#undef STOREKV
#undef LOADMSK

  // ---- cross-th reduction: partial O^T (f32) + partial l through LDS ----
  lr += __shfl_xor(lr, 32);                 // combine hi halves -> per-row partial for this th
  __syncthreads();                          // all waves done with Ks/Vs
  float* Of = (float*)sm;                   // [4 th][64 row][65]   (66560 B)
  float* Lf = (float*)sm + 4 * 64 * 65;     // [64 row][4 th]       (+1024 B) = 67584 B = LDS size
  {
    int row = wq2 * 32 + c;
#pragma unroll
    for (int r_ = 0; r_ < 16; ++r_) {
      int d = (r_ & 3) + 8 * (r_ >> 2) + 4 * hi;
      Of[(th * 64 + row) * 65 + d]      = o0[r_];
      Of[(th * 64 + row) * 65 + 32 + d] = o1[r_];
    }
    if (hi == 0) Lf[row * 4 + th] = lr;
  }
  __syncthreads();
  {
    int qrow = tid >> 3, d0 = (tid & 7) * 8;
    float lt = Lf[qrow * 4 + 0] + Lf[qrow * 4 + 1] + Lf[qrow * 4 + 2] + Lf[qrow * 4 + 3];
    float inv = 1.f / fmaxf(lt, 1e-20f);
    float acc[8];
#pragma unroll
    for (int e = 0; e < 8; ++e) acc[e] = 0.f;
#pragma unroll
    for (int t_ = 0; t_ < 4; ++t_)
#pragma unroll
      for (int e = 0; e < 8; ++e) acc[e] += Of[(t_ * 64 + qrow) * 65 + d0 + e];
    uint32_t dw[4];
#pragma unroll
    for (int e = 0; e < 4; ++e) dw[e] = pk2(acc[2 * e] * inv, acc[2 * e + 1] * inv);
    *(uint4*)(AO + qkbase + (size_t)(m0 + qrow) * EMB + d0) = *(uint4*)dw;
  }
}

extern "C" void kernel_launch(void* const* d_in, const int* in_sizes, int n_in,
                              void* d_out, int out_size, void* d_ws, size_t ws_size,
                              hipStream_t stream) {
  const float* q  = (const float*)d_in[0];
  const float* k  = (const float*)d_in[1];
  const float* v  = (const float*)d_in[2];
  const int* mask = (const int*)d_in[3];
  const float* Wq = (const float*)d_in[4];
  const float* Wk = (const float*)d_in[5];
  const float* Wv = (const float*)d_in[6];
  const float* W  = (const float*)d_in[7];
  float* out = (float*)d_out;

  // d_out (12 MiB) as scratch for Kp + Vt, dead before gemm_out writes.
  u16* Kp = (u16*)d_out;                    // [b,s,h*64+d] bf16
  u16* Vt = (u16*)d_out + 3145728;          // [bh][d][t]   bf16

  // ws: 11.5 MiB
  u16* ws    = (u16*)d_ws;
  u16* Qp    = ws;                          // 3145728 u16; AO aliases
  u16* WqkvT = ws + 3145728;                // 1769472 u16
  u16* WT    = ws + 3145728 + 1769472;      // 589824 u16
  uint64_t* mb64 = (uint64_t*)(ws + 5505024); // 131072 u64 = 1 MiB
  u16* AO = Qp;

  pack_w<<<dim3(576), 256, 0, stream>>>(Wq, Wk, Wv, W, WqkvT, WT);
  gemm_qkv<<<dim3(3200), 256, 0, stream>>>(q, k, v, WqkvT, mask, Qp, Kp, Vt, mb64);
  attn<<<dim3(768), 512, 0, stream>>>(Qp, Kp, Vt, mb64, AO);
  gemm_out<<<dim3(768), 256, 0, stream>>>(AO, WT, out);
}